// Round 1
// baseline (1107.896 us; speedup 1.0000x reference)
//
#include <hip/hip_runtime.h>
#include <stdint.h>

#define D_MODEL 1024
#define D_FF    4096
#define NE      8
#define T_TOK   4096
#define R_TOT   8192   // T_TOK * TOP_K, always exact (top-2 of 8 distinct)

typedef float f32x4 __attribute__((ext_vector_type(4)));
typedef __bf16 bf16x8 __attribute__((ext_vector_type(8)));
typedef unsigned short ushort_t;

__device__ __forceinline__ ushort_t f2bf(float f) {
    unsigned int u = __float_as_uint(f);
    u += 0x7FFFu + ((u >> 16) & 1u);   // round-to-nearest-even
    return (ushort_t)(u >> 16);
}

// async global->LDS, 16B per lane. Pass a WAVE-UNIFORM lds base; HW adds lane*16.
__device__ __forceinline__ void async16(const void* g, const void* l) {
    __builtin_amdgcn_global_load_lds(
        (const __attribute__((address_space(1))) unsigned int*)(uintptr_t)g,
        (__attribute__((address_space(3))) unsigned int*)(uintptr_t)l,
        16, 0, 0);
}

// ---------------- gate: one wave per token ----------------
__global__ __launch_bounds__(256) void k_gate(
    const float* __restrict__ x, const float* __restrict__ Wg, const float* __restrict__ bg,
    int* __restrict__ topi, float* __restrict__ topw, int* __restrict__ counts)
{
    int wave = threadIdx.x >> 6, lane = threadIdx.x & 63;
    int t = blockIdx.x * 4 + wave;
    const float* xr = x + (size_t)t * D_MODEL;
    float acc[NE];
#pragma unroll
    for (int e = 0; e < NE; ++e) acc[e] = 0.f;
#pragma unroll
    for (int i = 0; i < D_MODEL / 64; ++i) {
        int k = i * 64 + lane;
        float xv = xr[k];
        const float4* wgp = (const float4*)(Wg + (size_t)k * NE);
        float4 w0 = wgp[0], w1 = wgp[1];
        acc[0] += xv * w0.x; acc[1] += xv * w0.y; acc[2] += xv * w0.z; acc[3] += xv * w0.w;
        acc[4] += xv * w1.x; acc[5] += xv * w1.y; acc[6] += xv * w1.z; acc[7] += xv * w1.w;
    }
#pragma unroll
    for (int off = 32; off >= 1; off >>= 1)
#pragma unroll
        for (int e = 0; e < NE; ++e) acc[e] += __shfl_down(acc[e], off, 64);
    if (lane == 0) {
        float l[NE], m = -1e30f;
#pragma unroll
        for (int e = 0; e < NE; ++e) { l[e] = acc[e] + bg[e]; m = fmaxf(m, l[e]); }
        float p[NE], Z = 0.f;
#pragma unroll
        for (int e = 0; e < NE; ++e) { p[e] = __expf(l[e] - m); Z += p[e]; }
        float invZ = 1.f / Z;
        int i0 = 0; float v0 = -1.f;
#pragma unroll
        for (int e = 0; e < NE; ++e) { p[e] *= invZ; if (p[e] > v0) { v0 = p[e]; i0 = e; } }
        int i1 = 0; float v1 = -1.f;
#pragma unroll
        for (int e = 0; e < NE; ++e) { if (e != i0 && p[e] > v1) { v1 = p[e]; i1 = e; } }
        float denom = 1.f / (v0 + v1 + 1e-6f);
        topi[t * 2 + 0] = i0; topi[t * 2 + 1] = i1;
        topw[t * 2 + 0] = v0 * denom; topw[t * 2 + 1] = v1 * denom;
        atomicAdd(&counts[i0], 1); atomicAdd(&counts[i1], 1);
    }
}

// ---------------- tiny scan: offsets = exclusive prefix(counts) ----------------
__global__ void k_scan(const int* __restrict__ counts, int* __restrict__ offsets,
                       int* __restrict__ cursors)
{
    if (threadIdx.x == 0) {
        int acc = 0;
        for (int e = 0; e < NE; ++e) { offsets[e] = acc; cursors[e] = acc; acc += counts[e]; }
    }
}

// ---------------- scatter tokens into expert buckets ----------------
__global__ __launch_bounds__(256) void k_scatter(
    const int* __restrict__ topi, const float* __restrict__ topw,
    int* __restrict__ cursors, int* __restrict__ btok, float* __restrict__ bw)
{
    int t = blockIdx.x * 256 + threadIdx.x;
#pragma unroll
    for (int k = 0; k < 2; ++k) {
        int e = topi[t * 2 + k];
        int p = atomicAdd(&cursors[e], 1);
        btok[p] = t;
        bw[p] = topw[t * 2 + k];
    }
}

// ---------------- gather x rows (bucket order) + fp32->bf16 ----------------
__global__ __launch_bounds__(256) void k_gather(
    const float* __restrict__ x, const int* __restrict__ btok, ushort_t* __restrict__ Xg)
{
    int i = blockIdx.x;
    int t = btok[i];
    float4 v = ((const float4*)(x + (size_t)t * D_MODEL))[threadIdx.x];
    ushort4 o;
    o.x = f2bf(v.x); o.y = f2bf(v.y); o.z = f2bf(v.z); o.w = f2bf(v.w);
    ((ushort4*)(Xg + (size_t)i * D_MODEL))[threadIdx.x] = o;
}

// ---------------- weight transpose+convert: W[e][K][N] fp32 -> Wt[e][N][K] bf16 ----------------
__global__ __launch_bounds__(256) void k_transpose(
    const float* __restrict__ W, ushort_t* __restrict__ Wt, int K, int N)
{
    __shared__ ushort_t tile[64 * 72];
    int e = blockIdx.z;
    const float* We = W + (size_t)e * K * N;
    ushort_t* Wte = Wt + (size_t)e * K * N;
    int nb = blockIdx.x * 64, kb = blockIdx.y * 64;
    int tn4 = (threadIdx.x & 15) * 4;
    int tk = threadIdx.x >> 4;
#pragma unroll
    for (int r = 0; r < 4; ++r) {
        int k = r * 16 + tk;
        float4 v = *(const float4*)(We + (size_t)(kb + k) * N + nb + tn4);
        tile[(tn4 + 0) * 72 + k] = f2bf(v.x);
        tile[(tn4 + 1) * 72 + k] = f2bf(v.y);
        tile[(tn4 + 2) * 72 + k] = f2bf(v.z);
        tile[(tn4 + 3) * 72 + k] = f2bf(v.w);
    }
    __syncthreads();
#pragma unroll
    for (int c = 0; c < 4; ++c) {
        int chunk = c * 256 + threadIdx.x;
        int n = chunk >> 4, kc = (chunk & 15) * 4;
        ushort4 o = *(const ushort4*)&tile[n * 72 + kc];
        *(ushort4*)(Wte + (size_t)(nb + n) * K + kb + kc) = o;
    }
}

// ---------------- grouped GEMM1: H = silu(Xg@W1 + b1) * (Xg@W3 + b3) ----------------
__global__ __launch_bounds__(256) void k_gemm1(
    const ushort_t* __restrict__ Xg, const ushort_t* __restrict__ W1t,
    const ushort_t* __restrict__ W3t,
    const float* __restrict__ b1, const float* __restrict__ b3,
    const int* __restrict__ counts, const int* __restrict__ offsets,
    ushort_t* __restrict__ H)
{
    __shared__ __align__(16) ushort_t sA[128 * 32];
    __shared__ __align__(16) ushort_t sB1[128 * 32];
    __shared__ __align__(16) ushort_t sB3[128 * 32];

    int tm = blockIdx.x, e = 0, cnt = 0;
    for (; e < NE; ++e) {
        cnt = counts[e];
        int nt = (cnt + 127) >> 7;
        if (tm < nt) break;
        tm -= nt;
    }
    if (e >= NE) return;
    int row0 = offsets[e] + tm * 128;
    int rows_left = cnt - tm * 128;

    int tile_n = blockIdx.y * 128;
    int tid = threadIdx.x, wave = tid >> 6, lane = tid & 63;
    int wm = (wave >> 1) * 64, wn = (wave & 1) * 64;
    int col = lane & 15, quad = lane >> 4;

    const ushort_t* W1e = W1t + (size_t)e * D_FF * D_MODEL;
    const ushort_t* W3e = W3t + (size_t)e * D_FF * D_MODEL;

    f32x4 acc1[4][4], acc3[4][4];
#pragma unroll
    for (int i = 0; i < 4; ++i)
#pragma unroll
        for (int j = 0; j < 4; ++j) {
            acc1[i][j] = (f32x4){0.f, 0.f, 0.f, 0.f};
            acc3[i][j] = (f32x4){0.f, 0.f, 0.f, 0.f};
        }

    // staging: chunk q covers (row q>>2, 16B k-chunk q&3); lds dest = wave base + lane*16
    int q0 = wave * 128 + lane;          // inst 0
    int q1 = wave * 128 + 64 + lane;     // inst 1
    int am0 = q0 >> 2, ac0 = (q0 & 3) * 8;
    int am1 = q1 >> 2, ac1 = (q1 & 3) * 8;
    unsigned ab0 = (unsigned)(wave * 2 + 0) * 512;   // elem offset of wave-uniform lds base
    unsigned ab1 = (unsigned)(wave * 2 + 1) * 512;

    for (int k0 = 0; k0 < D_MODEL; k0 += 32) {
        async16(Xg + (size_t)(row0 + am0) * D_MODEL + k0 + ac0, sA + ab0);
        async16(Xg + (size_t)(row0 + am1) * D_MODEL + k0 + ac1, sA + ab1);
        async16(W1e + (size_t)(tile_n + am0) * D_MODEL + k0 + ac0, sB1 + ab0);
        async16(W1e + (size_t)(tile_n + am1) * D_MODEL + k0 + ac1, sB1 + ab1);
        async16(W3e + (size_t)(tile_n + am0) * D_MODEL + k0 + ac0, sB3 + ab0);
        async16(W3e + (size_t)(tile_n + am1) * D_MODEL + k0 + ac1, sB3 + ab1);
        __syncthreads();
        bf16x8 a[4], u1[4], u3[4];
#pragma unroll
        for (int i = 0; i < 4; ++i) {
            a[i]  = *(const bf16x8*)(sA  + (wm + i * 16 + col) * 32 + quad * 8);
            u1[i] = *(const bf16x8*)(sB1 + (wn + i * 16 + col) * 32 + quad * 8);
            u3[i] = *(const bf16x8*)(sB3 + (wn + i * 16 + col) * 32 + quad * 8);
        }
#pragma unroll
        for (int i = 0; i < 4; ++i)
#pragma unroll
            for (int j = 0; j < 4; ++j) {
                acc1[i][j] = __builtin_amdgcn_mfma_f32_16x16x32_bf16(a[i], u1[j], acc1[i][j], 0, 0, 0);
                acc3[i][j] = __builtin_amdgcn_mfma_f32_16x16x32_bf16(a[i], u3[j], acc3[i][j], 0, 0, 0);
            }
        __syncthreads();
    }

#pragma unroll
    for (int j = 0; j < 4; ++j) {
        int n = tile_n + wn + j * 16 + col;
        float bias1 = b1[e * D_FF + n];
        float bias3 = b3[e * D_FF + n];
#pragma unroll
        for (int i = 0; i < 4; ++i) {
            int rbase = wm + i * 16 + quad * 4;
#pragma unroll
            for (int r = 0; r < 4; ++r) {
                int row = rbase + r;
                if (row < rows_left) {
                    float h1 = acc1[i][j][r] + bias1;
                    float h3 = acc3[i][j][r] + bias3;
                    float s = h1 / (1.f + __expf(-h1));   // silu
                    H[(size_t)(row0 + row) * D_FF + n] = f2bf(s * h3);
                }
            }
        }
    }
}

// ---------------- grouped GEMM2: out[tok] += w * (H @ W2 + b2) ----------------
__global__ __launch_bounds__(256) void k_gemm2(
    const ushort_t* __restrict__ H, const ushort_t* __restrict__ W2t,
    const float* __restrict__ b2,
    const int* __restrict__ counts, const int* __restrict__ offsets,
    const int* __restrict__ btok, const float* __restrict__ bw,
    float* __restrict__ out)
{
    __shared__ __align__(16) ushort_t sA[128 * 32];
    __shared__ __align__(16) ushort_t sB[128 * 32];

    int tm = blockIdx.x, e = 0, cnt = 0;
    for (; e < NE; ++e) {
        cnt = counts[e];
        int nt = (cnt + 127) >> 7;
        if (tm < nt) break;
        tm -= nt;
    }
    if (e >= NE) return;
    int row0 = offsets[e] + tm * 128;
    int rows_left = cnt - tm * 128;

    int tile_n = blockIdx.y * 128;
    int tid = threadIdx.x, wave = tid >> 6, lane = tid & 63;
    int wm = (wave >> 1) * 64, wn = (wave & 1) * 64;
    int col = lane & 15, quad = lane >> 4;

    const ushort_t* W2e = W2t + (size_t)e * D_MODEL * D_FF;

    f32x4 acc[4][4];
#pragma unroll
    for (int i = 0; i < 4; ++i)
#pragma unroll
        for (int j = 0; j < 4; ++j) acc[i][j] = (f32x4){0.f, 0.f, 0.f, 0.f};

    int q0 = wave * 128 + lane;
    int q1 = wave * 128 + 64 + lane;
    int am0 = q0 >> 2, ac0 = (q0 & 3) * 8;
    int am1 = q1 >> 2, ac1 = (q1 & 3) * 8;
    unsigned ab0 = (unsigned)(wave * 2 + 0) * 512;
    unsigned ab1 = (unsigned)(wave * 2 + 1) * 512;

    for (int k0 = 0; k0 < D_FF; k0 += 32) {
        async16(H + (size_t)(row0 + am0) * D_FF + k0 + ac0, sA + ab0);
        async16(H + (size_t)(row0 + am1) * D_FF + k0 + ac1, sA + ab1);
        async16(W2e + (size_t)(tile_n + am0) * D_FF + k0 + ac0, sB + ab0);
        async16(W2e + (size_t)(tile_n + am1) * D_FF + k0 + ac1, sB + ab1);
        __syncthreads();
        bf16x8 a[4], b[4];
#pragma unroll
        for (int i = 0; i < 4; ++i) {
            a[i] = *(const bf16x8*)(sA + (wm + i * 16 + col) * 32 + quad * 8);
            b[i] = *(const bf16x8*)(sB + (wn + i * 16 + col) * 32 + quad * 8);
        }
#pragma unroll
        for (int i = 0; i < 4; ++i)
#pragma unroll
            for (int j = 0; j < 4; ++j)
                acc[i][j] = __builtin_amdgcn_mfma_f32_16x16x32_bf16(a[i], b[j], acc[i][j], 0, 0, 0);
        __syncthreads();
    }

    float bias[4];
#pragma unroll
    for (int j = 0; j < 4; ++j) bias[j] = b2[e * D_MODEL + tile_n + wn + j * 16 + col];

#pragma unroll
    for (int i = 0; i < 4; ++i) {
        int rbase = wm + i * 16 + quad * 4;
#pragma unroll
        for (int r = 0; r < 4; ++r) {
            int row = rbase + r;
            if (row < rows_left) {
                int g_r = row0 + row;
                int t = btok[g_r];
                float w = bw[g_r];
                float* orow = out + (size_t)t * D_MODEL + tile_n + wn + col;
#pragma unroll
                for (int j = 0; j < 4; ++j)
                    atomicAdd(orow + j * 16, w * (acc[i][j][r] + bias[j]));
            }
        }
    }
}

extern "C" void kernel_launch(void* const* d_in, const int* in_sizes, int n_in,
                              void* d_out, int out_size, void* d_ws, size_t ws_size,
                              hipStream_t stream)
{
    const float* x  = (const float*)d_in[0];
    const float* Wg = (const float*)d_in[1];
    const float* bg = (const float*)d_in[2];
    const float* W1 = (const float*)d_in[3];
    const float* b1 = (const float*)d_in[4];
    const float* W3 = (const float*)d_in[5];
    const float* b3 = (const float*)d_in[6];
    const float* W2 = (const float*)d_in[7];
    const float* b2 = (const float*)d_in[8];
    float* out = (float*)d_out;

    char* ws = (char*)d_ws;
    int*   counts  = (int*)(ws + 0);
    int*   cursors = (int*)(ws + 32);
    int*   offsets = (int*)(ws + 64);
    int*   topi    = (int*)(ws + 256);
    float* topw    = (float*)(ws + 256 + 32768);
    int*   btok    = (int*)(ws + 256 + 65536);
    float* bw      = (float*)(ws + 256 + 98304);
    char* p = ws + 131328;
    ushort_t* Xg  = (ushort_t*)p;  p += (size_t)R_TOT * D_MODEL * 2;      // 16.78 MB
    ushort_t* Hb  = (ushort_t*)p;  p += (size_t)R_TOT * D_FF * 2;         // 67.1 MB
    ushort_t* W1t = (ushort_t*)p;  p += (size_t)NE * D_FF * D_MODEL * 2;  // 67.1 MB
    ushort_t* W3t = (ushort_t*)p;  p += (size_t)NE * D_FF * D_MODEL * 2;  // 67.1 MB
    ushort_t* W2t = (ushort_t*)p;                                          // 67.1 MB

    hipMemsetAsync(ws, 0, 64, stream);                       // counts + cursors
    hipMemsetAsync(d_out, 0, (size_t)out_size * 4, stream);  // atomics accumulate into out

    k_gate<<<dim3(T_TOK / 4), dim3(256), 0, stream>>>(x, Wg, bg, topi, topw, counts);
    k_scan<<<dim3(1), dim3(64), 0, stream>>>(counts, offsets, cursors);
    k_scatter<<<dim3(T_TOK / 256), dim3(256), 0, stream>>>(topi, topw, cursors, btok, bw);
    k_gather<<<dim3(R_TOT), dim3(256), 0, stream>>>(x, btok, Xg);
    k_transpose<<<dim3(D_FF / 64, D_MODEL / 64, NE), dim3(256), 0, stream>>>(W1, W1t, D_MODEL, D_FF);
    k_transpose<<<dim3(D_FF / 64, D_MODEL / 64, NE), dim3(256), 0, stream>>>(W3, W3t, D_MODEL, D_FF);
    k_transpose<<<dim3(D_MODEL / 64, D_FF / 64, NE), dim3(256), 0, stream>>>(W2, W2t, D_FF, D_MODEL);
    k_gemm1<<<dim3(72, D_FF / 128), dim3(256), 0, stream>>>(Xg, W1t, W3t, b1, b3, counts, offsets, Hb);
    k_gemm2<<<dim3(72, D_MODEL / 128), dim3(256), 0, stream>>>(Hb, W2t, b2, counts, offsets, btok, bw, out);
}

// Round 2
// 914.875 us; speedup vs baseline: 1.2110x; 1.2110x over previous
//
#include <hip/hip_runtime.h>
#include <stdint.h>

#define D_MODEL 1024
#define D_FF    4096
#define NE      8
#define T_TOK   4096
#define R_TOT   8192   // T_TOK * TOP_K, always exact (top-2 of 8 distinct)

typedef float f32x4 __attribute__((ext_vector_type(4)));
typedef __bf16 bf16x8 __attribute__((ext_vector_type(8)));
typedef unsigned short ushort_t;

__device__ __forceinline__ ushort_t f2bf(float f) {
    unsigned int u = __float_as_uint(f);
    u += 0x7FFFu + ((u >> 16) & 1u);   // round-to-nearest-even
    return (ushort_t)(u >> 16);
}

// async global->LDS, 16B per lane. Pass a WAVE-UNIFORM lds base; HW adds lane*16.
__device__ __forceinline__ void async16(const void* g, const void* l) {
    __builtin_amdgcn_global_load_lds(
        (const __attribute__((address_space(1))) unsigned int*)(uintptr_t)g,
        (__attribute__((address_space(3))) unsigned int*)(uintptr_t)l,
        16, 0, 0);
}

// ---------------- gate: one wave per token ----------------
__global__ __launch_bounds__(256) void k_gate(
    const float* __restrict__ x, const float* __restrict__ Wg, const float* __restrict__ bg,
    int* __restrict__ topi, float* __restrict__ topw, int* __restrict__ counts)
{
    int wave = threadIdx.x >> 6, lane = threadIdx.x & 63;
    int t = blockIdx.x * 4 + wave;
    const float* xr = x + (size_t)t * D_MODEL;
    float acc[NE];
#pragma unroll
    for (int e = 0; e < NE; ++e) acc[e] = 0.f;
#pragma unroll
    for (int i = 0; i < D_MODEL / 64; ++i) {
        int k = i * 64 + lane;
        float xv = xr[k];
        const float4* wgp = (const float4*)(Wg + (size_t)k * NE);
        float4 w0 = wgp[0], w1 = wgp[1];
        acc[0] += xv * w0.x; acc[1] += xv * w0.y; acc[2] += xv * w0.z; acc[3] += xv * w0.w;
        acc[4] += xv * w1.x; acc[5] += xv * w1.y; acc[6] += xv * w1.z; acc[7] += xv * w1.w;
    }
#pragma unroll
    for (int off = 32; off >= 1; off >>= 1)
#pragma unroll
        for (int e = 0; e < NE; ++e) acc[e] += __shfl_down(acc[e], off, 64);
    if (lane == 0) {
        float l[NE], m = -1e30f;
#pragma unroll
        for (int e = 0; e < NE; ++e) { l[e] = acc[e] + bg[e]; m = fmaxf(m, l[e]); }
        float p[NE], Z = 0.f;
#pragma unroll
        for (int e = 0; e < NE; ++e) { p[e] = __expf(l[e] - m); Z += p[e]; }
        float invZ = 1.f / Z;
        int i0 = 0; float v0 = -1.f;
#pragma unroll
        for (int e = 0; e < NE; ++e) { p[e] *= invZ; if (p[e] > v0) { v0 = p[e]; i0 = e; } }
        int i1 = 0; float v1 = -1.f;
#pragma unroll
        for (int e = 0; e < NE; ++e) { if (e != i0 && p[e] > v1) { v1 = p[e]; i1 = e; } }
        float denom = 1.f / (v0 + v1 + 1e-6f);
        topi[t * 2 + 0] = i0; topi[t * 2 + 1] = i1;
        topw[t * 2 + 0] = v0 * denom; topw[t * 2 + 1] = v1 * denom;
        atomicAdd(&counts[i0], 1); atomicAdd(&counts[i1], 1);
    }
}

// ---------------- tiny scan ----------------
__global__ void k_scan(const int* __restrict__ counts, int* __restrict__ offsets,
                       int* __restrict__ cursors)
{
    if (threadIdx.x == 0) {
        int acc = 0;
        for (int e = 0; e < NE; ++e) { offsets[e] = acc; cursors[e] = acc; acc += counts[e]; }
    }
}

// ---------------- scatter tokens into expert buckets ----------------
__global__ __launch_bounds__(256) void k_scatter(
    const int* __restrict__ topi, const float* __restrict__ topw,
    int* __restrict__ cursors, int* __restrict__ btok, float* __restrict__ bw)
{
    int t = blockIdx.x * 256 + threadIdx.x;
#pragma unroll
    for (int k = 0; k < 2; ++k) {
        int e = topi[t * 2 + k];
        int p = atomicAdd(&cursors[e], 1);
        btok[p] = t;
        bw[p] = topw[t * 2 + k];
    }
}

// ---------------- gather x rows (bucket order) + fp32->bf16 ----------------
__global__ __launch_bounds__(256) void k_gather(
    const float* __restrict__ x, const int* __restrict__ btok, ushort_t* __restrict__ Xg)
{
    int i = blockIdx.x;
    int t = btok[i];
    float4 v = ((const float4*)(x + (size_t)t * D_MODEL))[threadIdx.x];
    ushort4 o;
    o.x = f2bf(v.x); o.y = f2bf(v.y); o.z = f2bf(v.z); o.w = f2bf(v.w);
    ((ushort4*)(Xg + (size_t)i * D_MODEL))[threadIdx.x] = o;
}

// ---------------- weight transpose+convert: W[e][K][N] fp32 -> Wt[e][N][K] bf16 ----------------
__global__ __launch_bounds__(256) void k_transpose(
    const float* __restrict__ W, ushort_t* __restrict__ Wt, int K, int N)
{
    __shared__ ushort_t tile[64 * 72];
    int e = blockIdx.z;
    const float* We = W + (size_t)e * K * N;
    ushort_t* Wte = Wt + (size_t)e * K * N;
    int nb = blockIdx.x * 64, kb = blockIdx.y * 64;
    int tn4 = (threadIdx.x & 15) * 4;
    int tk = threadIdx.x >> 4;
#pragma unroll
    for (int r = 0; r < 4; ++r) {
        int k = r * 16 + tk;
        float4 v = *(const float4*)(We + (size_t)(kb + k) * N + nb + tn4);
        tile[(tn4 + 0) * 72 + k] = f2bf(v.x);
        tile[(tn4 + 1) * 72 + k] = f2bf(v.y);
        tile[(tn4 + 2) * 72 + k] = f2bf(v.z);
        tile[(tn4 + 3) * 72 + k] = f2bf(v.w);
    }
    __syncthreads();
#pragma unroll
    for (int c = 0; c < 4; ++c) {
        int chunk = c * 256 + threadIdx.x;
        int n = chunk >> 4, kc = (chunk & 15) * 4;
        ushort4 o = *(const ushort4*)&tile[n * 72 + kc];
        *(ushort4*)(Wte + (size_t)(nb + n) * K + kb + kc) = o;
    }
}

// Staged LDS layout (BK=64): tile is 128 rows x 64 elems. Row = 128 B. The 8
// 16B-chunks of row r are stored XOR-swizzled: chunk c_glob lives at LDS slot
// c_glob ^ (r & 7). Swizzle applied on the GLOBAL address of global_load_lds
// (LDS side is HW-fixed wave base + lane*16) and un-done on the ds_read side.

// ---------------- grouped GEMM1: H = silu(Xg@W1 + b1) * (Xg@W3 + b3) ----------------
__global__ __launch_bounds__(256, 2) void k_gemm1(
    const ushort_t* __restrict__ Xg, const ushort_t* __restrict__ W1t,
    const ushort_t* __restrict__ W3t,
    const float* __restrict__ b1, const float* __restrict__ b3,
    const int* __restrict__ counts, const int* __restrict__ offsets,
    ushort_t* __restrict__ H)
{
    __shared__ __align__(16) ushort_t sA[128 * 64];
    __shared__ __align__(16) ushort_t sB1[128 * 64];
    __shared__ __align__(16) ushort_t sB3[128 * 64];

    int tm = blockIdx.x, e = 0, cnt = 0;
    for (; e < NE; ++e) {
        cnt = counts[e];
        int nt = (cnt + 127) >> 7;
        if (tm < nt) break;
        tm -= nt;
    }
    if (e >= NE) return;
    int row0 = offsets[e] + tm * 128;
    int rows_left = cnt - tm * 128;

    int tile_n = blockIdx.y * 128;
    int tid = threadIdx.x, wave = tid >> 6, lane = tid & 63;
    int wm = (wave >> 1) * 64, wn = (wave & 1) * 64;
    int col = lane & 15, quad = lane >> 4;

    const ushort_t* W1e = W1t + (size_t)e * D_FF * D_MODEL;
    const ushort_t* W3e = W3t + (size_t)e * D_FF * D_MODEL;

    // staging source pointers (swizzled) + uniform lds bases
    const ushort_t* gA[4]; const ushort_t* gB1[4]; const ushort_t* gB3[4];
    unsigned ldsOff[4];
#pragma unroll
    for (int s = 0; s < 4; ++s) {
        int q = (wave * 4 + s) * 64 + lane;
        int r = q >> 3;
        int cg = ((q & 7) ^ (r & 7)) * 8;
        gA[s]  = Xg  + (size_t)(row0 + r) * D_MODEL + cg;
        gB1[s] = W1e + (size_t)(tile_n + r) * D_MODEL + cg;
        gB3[s] = W3e + (size_t)(tile_n + r) * D_MODEL + cg;
        ldsOff[s] = (unsigned)(wave * 4 + s) * 512;
    }
    // frag lds offsets: row*64 + swz, toggle ^32 for kk=32
    int swz = (quad ^ (col & 7)) * 8;
    unsigned fA[4], fB[4];
#pragma unroll
    for (int i = 0; i < 4; ++i) {
        fA[i] = (unsigned)(wm + i * 16 + col) * 64 + swz;
        fB[i] = (unsigned)(wn + i * 16 + col) * 64 + swz;
    }

    f32x4 acc1[4][4], acc3[4][4];
#pragma unroll
    for (int i = 0; i < 4; ++i)
#pragma unroll
        for (int j = 0; j < 4; ++j) {
            acc1[i][j] = (f32x4){0.f, 0.f, 0.f, 0.f};
            acc3[i][j] = (f32x4){0.f, 0.f, 0.f, 0.f};
        }

    for (int k0 = 0; k0 < D_MODEL; k0 += 64) {
#pragma unroll
        for (int s = 0; s < 4; ++s) {
            async16(gA[s]  + k0, sA  + ldsOff[s]);
            async16(gB1[s] + k0, sB1 + ldsOff[s]);
            async16(gB3[s] + k0, sB3 + ldsOff[s]);
        }
        __syncthreads();
#pragma unroll
        for (int kk = 0; kk < 2; ++kk) {
            unsigned kx = kk * 32;
            bf16x8 u1[4], u3[4];
#pragma unroll
            for (int j = 0; j < 4; ++j) {
                u1[j] = *(const bf16x8*)(sB1 + (fB[j] ^ kx));
                u3[j] = *(const bf16x8*)(sB3 + (fB[j] ^ kx));
            }
#pragma unroll
            for (int i = 0; i < 4; ++i) {
                bf16x8 a = *(const bf16x8*)(sA + (fA[i] ^ kx));
#pragma unroll
                for (int j = 0; j < 4; ++j) {
                    acc1[i][j] = __builtin_amdgcn_mfma_f32_16x16x32_bf16(a, u1[j], acc1[i][j], 0, 0, 0);
                    acc3[i][j] = __builtin_amdgcn_mfma_f32_16x16x32_bf16(a, u3[j], acc3[i][j], 0, 0, 0);
                }
            }
        }
        __syncthreads();
    }

#pragma unroll
    for (int j = 0; j < 4; ++j) {
        int n = tile_n + wn + j * 16 + col;
        float bias1 = b1[e * D_FF + n];
        float bias3 = b3[e * D_FF + n];
#pragma unroll
        for (int i = 0; i < 4; ++i) {
            int rbase = wm + i * 16 + quad * 4;
#pragma unroll
            for (int r = 0; r < 4; ++r) {
                int row = rbase + r;
                if (row < rows_left) {
                    float h1 = acc1[i][j][r] + bias1;
                    float h3 = acc3[i][j][r] + bias3;
                    float s = h1 / (1.f + __expf(-h1));   // silu
                    H[(size_t)(row0 + row) * D_FF + n] = f2bf(s * h3);
                }
            }
        }
    }
}

// ---------------- grouped GEMM2: out[tok] += w * (H @ W2 + b2) ----------------
__global__ __launch_bounds__(256, 2) void k_gemm2(
    const ushort_t* __restrict__ H, const ushort_t* __restrict__ W2t,
    const float* __restrict__ b2,
    const int* __restrict__ counts, const int* __restrict__ offsets,
    const int* __restrict__ btok, const float* __restrict__ bw,
    float* __restrict__ out)
{
    __shared__ __align__(16) ushort_t sA[128 * 64];
    __shared__ __align__(16) ushort_t sB[128 * 64];

    int tm = blockIdx.x, e = 0, cnt = 0;
    for (; e < NE; ++e) {
        cnt = counts[e];
        int nt = (cnt + 127) >> 7;
        if (tm < nt) break;
        tm -= nt;
    }
    if (e >= NE) return;
    int row0 = offsets[e] + tm * 128;
    int rows_left = cnt - tm * 128;

    int tile_n = blockIdx.y * 128;
    int tid = threadIdx.x, wave = tid >> 6, lane = tid & 63;
    int wm = (wave >> 1) * 64, wn = (wave & 1) * 64;
    int col = lane & 15, quad = lane >> 4;

    const ushort_t* W2e = W2t + (size_t)e * D_MODEL * D_FF;

    const ushort_t* gA[4]; const ushort_t* gB[4];
    unsigned ldsOff[4];
#pragma unroll
    for (int s = 0; s < 4; ++s) {
        int q = (wave * 4 + s) * 64 + lane;
        int r = q >> 3;
        int cg = ((q & 7) ^ (r & 7)) * 8;
        gA[s] = H   + (size_t)(row0 + r) * D_FF + cg;
        gB[s] = W2e + (size_t)(tile_n + r) * D_FF + cg;
        ldsOff[s] = (unsigned)(wave * 4 + s) * 512;
    }
    int swz = (quad ^ (col & 7)) * 8;
    unsigned fA[4], fB[4];
#pragma unroll
    for (int i = 0; i < 4; ++i) {
        fA[i] = (unsigned)(wm + i * 16 + col) * 64 + swz;
        fB[i] = (unsigned)(wn + i * 16 + col) * 64 + swz;
    }

    f32x4 acc[4][4];
#pragma unroll
    for (int i = 0; i < 4; ++i)
#pragma unroll
        for (int j = 0; j < 4; ++j) acc[i][j] = (f32x4){0.f, 0.f, 0.f, 0.f};

    for (int k0 = 0; k0 < D_FF; k0 += 64) {
#pragma unroll
        for (int s = 0; s < 4; ++s) {
            async16(gA[s] + k0, sA + ldsOff[s]);
            async16(gB[s] + k0, sB + ldsOff[s]);
        }
        __syncthreads();
#pragma unroll
        for (int kk = 0; kk < 2; ++kk) {
            unsigned kx = kk * 32;
            bf16x8 b[4];
#pragma unroll
            for (int j = 0; j < 4; ++j) b[j] = *(const bf16x8*)(sB + (fB[j] ^ kx));
#pragma unroll
            for (int i = 0; i < 4; ++i) {
                bf16x8 a = *(const bf16x8*)(sA + (fA[i] ^ kx));
#pragma unroll
                for (int j = 0; j < 4; ++j)
                    acc[i][j] = __builtin_amdgcn_mfma_f32_16x16x32_bf16(a, b[j], acc[i][j], 0, 0, 0);
            }
        }
        __syncthreads();
    }

    float bias[4];
#pragma unroll
    for (int j = 0; j < 4; ++j) bias[j] = b2[e * D_MODEL + tile_n + wn + j * 16 + col];

#pragma unroll
    for (int i = 0; i < 4; ++i) {
        int rbase = wm + i * 16 + quad * 4;
#pragma unroll
        for (int r = 0; r < 4; ++r) {
            int row = rbase + r;
            if (row < rows_left) {
                int g_r = row0 + row;
                int t = btok[g_r];
                float w = bw[g_r];
                float* orow = out + (size_t)t * D_MODEL + tile_n + wn + col;
#pragma unroll
                for (int j = 0; j < 4; ++j)
                    atomicAdd(orow + j * 16, w * (acc[i][j][r] + bias[j]));
            }
        }
    }
}

extern "C" void kernel_launch(void* const* d_in, const int* in_sizes, int n_in,
                              void* d_out, int out_size, void* d_ws, size_t ws_size,
                              hipStream_t stream)
{
    const float* x  = (const float*)d_in[0];
    const float* Wg = (const float*)d_in[1];
    const float* bg = (const float*)d_in[2];
    const float* W1 = (const float*)d_in[3];
    const float* b1 = (const float*)d_in[4];
    const float* W3 = (const float*)d_in[5];
    const float* b3 = (const float*)d_in[6];
    const float* W2 = (const float*)d_in[7];
    const float* b2 = (const float*)d_in[8];
    float* out = (float*)d_out;

    char* ws = (char*)d_ws;
    int*   counts  = (int*)(ws + 0);
    int*   cursors = (int*)(ws + 32);
    int*   offsets = (int*)(ws + 64);
    int*   topi    = (int*)(ws + 256);
    float* topw    = (float*)(ws + 256 + 32768);
    int*   btok    = (int*)(ws + 256 + 65536);
    float* bw      = (float*)(ws + 256 + 98304);
    char* p = ws + 131328;
    ushort_t* Xg  = (ushort_t*)p;  p += (size_t)R_TOT * D_MODEL * 2;      // 16.78 MB
    ushort_t* Hb  = (ushort_t*)p;  p += (size_t)R_TOT * D_FF * 2;         // 67.1 MB
    ushort_t* W1t = (ushort_t*)p;  p += (size_t)NE * D_FF * D_MODEL * 2;  // 67.1 MB
    ushort_t* W3t = (ushort_t*)p;  p += (size_t)NE * D_FF * D_MODEL * 2;  // 67.1 MB
    ushort_t* W2t = (ushort_t*)p;                                          // 67.1 MB

    hipMemsetAsync(ws, 0, 64, stream);                       // counts + cursors
    hipMemsetAsync(d_out, 0, (size_t)out_size * 4, stream);  // atomics accumulate into out

    k_gate<<<dim3(T_TOK / 4), dim3(256), 0, stream>>>(x, Wg, bg, topi, topw, counts);
    k_scan<<<dim3(1), dim3(64), 0, stream>>>(counts, offsets, cursors);
    k_scatter<<<dim3(T_TOK / 256), dim3(256), 0, stream>>>(topi, topw, cursors, btok, bw);
    k_gather<<<dim3(R_TOT), dim3(256), 0, stream>>>(x, btok, Xg);
    k_transpose<<<dim3(D_FF / 64, D_MODEL / 64, NE), dim3(256), 0, stream>>>(W1, W1t, D_MODEL, D_FF);
    k_transpose<<<dim3(D_FF / 64, D_MODEL / 64, NE), dim3(256), 0, stream>>>(W3, W3t, D_MODEL, D_FF);
    k_transpose<<<dim3(D_MODEL / 64, D_FF / 64, NE), dim3(256), 0, stream>>>(W2, W2t, D_FF, D_MODEL);
    k_gemm1<<<dim3(72, D_FF / 128), dim3(256), 0, stream>>>(Xg, W1t, W3t, b1, b3, counts, offsets, Hb);
    k_gemm2<<<dim3(72, D_MODEL / 128), dim3(256), 0, stream>>>(Hb, W2t, b2, counts, offsets, btok, bw, out);
}